// Round 1
// baseline (97.218 us; speedup 1.0000x reference)
//
#include <hip/hip_runtime.h>

typedef _Float16 half8 __attribute__((ext_vector_type(8)));
typedef float f32x4 __attribute__((ext_vector_type(4)));

#define DD 128

// ---------------------------------------------------------------------------
// Precompute 1: split embed into f16 hi/lo, laid out in MFMA B-fragment order.
// Fragment slot convention (same bijection used for A in the main kernel):
//   chunk c (16 codes), k-step s (K=32), lane l:
//     code n = c*16 + (l&15), k = s*32 + (l>>4)*8 + b, b=0..7
//   stored contiguously: frag[t] at t = (c*4+s)*64 + l, 8 halves each.
// ---------------------------------------------------------------------------
__global__ void prep_frags_kernel(const float* __restrict__ embed,
                                  _Float16* __restrict__ eh,
                                  _Float16* __restrict__ el,
                                  int total) {
  int t = blockIdx.x * blockDim.x + threadIdx.x;
  if (t >= total) return;
  int l = t & 63;
  int s = (t >> 6) & 3;
  int c = t >> 8;
  int n = c * 16 + (l & 15);
  int kb = s * 32 + ((l >> 4) << 3);
  const float* src = embed + (size_t)n * DD + kb;
  _Float16* dh = eh + (size_t)t * 8;
  _Float16* dl = el + (size_t)t * 8;
#pragma unroll
  for (int j = 0; j < 8; ++j) {
    float v = src[j];
    _Float16 hi = (_Float16)v;
    dh[j] = hi;
    dl[j] = (_Float16)(v - (float)hi);
  }
}

// Precompute 2: ||e||^2 per code, in double (argmax tie robustness).
__global__ void prep_e2_kernel(const float* __restrict__ embed,
                               double* __restrict__ e2d, int K) {
  int n = blockIdx.x * blockDim.x + threadIdx.x;
  if (n >= K) return;
  const float* src = embed + (size_t)n * DD;
  double s = 0.0;
  for (int j = 0; j < DD; ++j) { double v = (double)src[j]; s += v * v; }
  e2d[n] = s;
}

// ---------------------------------------------------------------------------
// Main: per block 64 rows (4 waves x 16 rows). Each wave:
//   A frags (x rows, f16 hi/lo split) in registers, loop over 64 chunks of
//   16 codes: 12x mfma_f32_16x16x32_f16 (hh + lh + hl chained into one acc),
//   score = 2*acc - e2 in double, running argmax. Cross-lane reduce over the
//   16 lanes that share each C row, then write index + gather code row.
// C/D layout (verified): col = lane&15, row = (lane>>4)*4 + reg.
// ---------------------------------------------------------------------------
__global__ __launch_bounds__(256) void vq_argmin_kernel(
    const float* __restrict__ x, const float* __restrict__ embed,
    const _Float16* __restrict__ ehf, const _Float16* __restrict__ elf,
    const double* __restrict__ e2d,
    float* __restrict__ out_q, float* __restrict__ out_i, int K) {
  const int lane = threadIdx.x & 63;
  const int w = threadIdx.x >> 6;
  const int m16 = lane & 15;
  const int g = lane >> 4;
  const int row0 = blockIdx.x * 64 + w * 16;

  // A fragments: lane reads x[row0 + (lane&15)][s*32 + g*8 .. +8), split hi/lo
  half8 ah[4], al[4];
  const float* xrow = x + (size_t)(row0 + m16) * DD;
#pragma unroll
  for (int s = 0; s < 4; ++s) {
    const float* p = xrow + s * 32 + g * 8;
    f32x4 v0 = *(const f32x4*)(p);
    f32x4 v1 = *(const f32x4*)(p + 4);
#pragma unroll
    for (int j = 0; j < 4; ++j) {
      float v = v0[j];
      _Float16 hi = (_Float16)v;
      ah[s][j] = hi;
      al[s][j] = (_Float16)(v - (float)hi);
    }
#pragma unroll
    for (int j = 0; j < 4; ++j) {
      float v = v1[j];
      _Float16 hi = (_Float16)v;
      ah[s][4 + j] = hi;
      al[s][4 + j] = (_Float16)(v - (float)hi);
    }
  }

  double bestv[4];
  int besti[4];
#pragma unroll
  for (int r = 0; r < 4; ++r) { bestv[r] = -1e300; besti[r] = 0; }

  const half8* EH = (const half8*)ehf;
  const half8* EL = (const half8*)elf;
  const int nch = K >> 4;

  // preload chunk 0 B-fragments
  half8 bh[4], bl[4];
#pragma unroll
  for (int s = 0; s < 4; ++s) {
    bh[s] = EH[(size_t)s * 64 + lane];
    bl[s] = EL[(size_t)s * 64 + lane];
  }

  for (int c = 0; c < nch; ++c) {
    half8 nbh[4], nbl[4];
    if (c + 1 < nch) {
#pragma unroll
      for (int s = 0; s < 4; ++s) {
        nbh[s] = EH[((size_t)(c + 1) * 4 + s) * 64 + lane];
        nbl[s] = EL[((size_t)(c + 1) * 4 + s) * 64 + lane];
      }
    }
    f32x4 acc = {0.f, 0.f, 0.f, 0.f};
#pragma unroll
    for (int s = 0; s < 4; ++s) {
      acc = __builtin_amdgcn_mfma_f32_16x16x32_f16(ah[s], bh[s], acc, 0, 0, 0);
      acc = __builtin_amdgcn_mfma_f32_16x16x32_f16(al[s], bh[s], acc, 0, 0, 0);
      acc = __builtin_amdgcn_mfma_f32_16x16x32_f16(ah[s], bl[s], acc, 0, 0, 0);
    }
    const int n = (c << 4) + m16;
    const double e2 = e2d[n];
#pragma unroll
    for (int r = 0; r < 4; ++r) {
      double sc = 2.0 * (double)acc[r] - e2;
      if (sc > bestv[r]) { bestv[r] = sc; besti[r] = n; }
    }
#pragma unroll
    for (int s = 0; s < 4; ++s) { bh[s] = nbh[s]; bl[s] = nbl[s]; }
  }

  // reduce across the 16 lanes (columns) sharing each C row; prefer smaller
  // index on exact tie (matches argmax first-max semantics).
#pragma unroll
  for (int off = 1; off < 16; off <<= 1) {
#pragma unroll
    for (int r = 0; r < 4; ++r) {
      double ov = __shfl_xor(bestv[r], off, 64);
      int oi = __shfl_xor(besti[r], off, 64);
      if (ov > bestv[r] || (ov == bestv[r] && oi < besti[r])) {
        bestv[r] = ov;
        besti[r] = oi;
      }
    }
  }

  // outputs: index (as float) + gathered code row (16 lanes x 8 floats)
#pragma unroll
  for (int r = 0; r < 4; ++r) {
    const int row = row0 + g * 4 + r;
    const int idx = besti[r];
    if (m16 == 0) out_i[row] = (float)idx;
    const f32x4* src = (const f32x4*)(embed + (size_t)idx * DD) + m16 * 2;
    f32x4* dst = (f32x4*)(out_q + (size_t)row * DD) + m16 * 2;
    dst[0] = src[0];
    dst[1] = src[1];
  }
}

// ---------------------------------------------------------------------------
// Fallback (only if workspace is unexpectedly small): exact double-precision
// distance, thread per row. Slow but correct.
// ---------------------------------------------------------------------------
__global__ void vq_fallback_kernel(const float* __restrict__ x,
                                   const float* __restrict__ embed,
                                   float* __restrict__ out_q,
                                   float* __restrict__ out_i, int N, int K) {
  int row = blockIdx.x * blockDim.x + threadIdx.x;
  if (row >= N) return;
  const float* xr = x + (size_t)row * DD;
  float xv[DD];
  for (int j = 0; j < DD; ++j) xv[j] = xr[j];
  double best = -1e300;
  int bi = 0;
  for (int k = 0; k < K; ++k) {
    const float* e = embed + (size_t)k * DD;
    double acc = 0.0;
    for (int j = 0; j < DD; ++j) {
      double d = (double)xv[j] - (double)e[j];
      acc += d * d;
    }
    double sc = -acc;
    if (sc > best) { best = sc; bi = k; }
  }
  out_i[row] = (float)bi;
  for (int j = 0; j < DD; ++j)
    out_q[(size_t)row * DD + j] = embed[(size_t)bi * DD + j];
}

extern "C" void kernel_launch(void* const* d_in, const int* in_sizes, int n_in,
                              void* d_out, int out_size, void* d_ws,
                              size_t ws_size, hipStream_t stream) {
  const float* x = (const float*)d_in[0];
  const float* embed = (const float*)d_in[1];
  const int N = in_sizes[0] / DD;  // 65536 rows
  const int K = in_sizes[1] / DD;  // 1024 codes
  float* out_q = (float*)d_out;
  float* out_i = out_q + (size_t)N * DD;

  const size_t e2_bytes = ((size_t)K * 8 + 255) / 256 * 256;
  const size_t frag_halves = (size_t)K * DD;  // per hi/lo buffer
  const size_t need = e2_bytes + 2 * frag_halves * sizeof(_Float16);

  if (ws_size < need || (N % 64) != 0 || (K % 16) != 0) {
    vq_fallback_kernel<<<(N + 255) / 256, 256, 0, stream>>>(x, embed, out_q,
                                                            out_i, N, K);
    return;
  }

  double* e2d = (double*)d_ws;
  _Float16* eh = (_Float16*)((char*)d_ws + e2_bytes);
  _Float16* el = eh + frag_halves;

  const int total = (K / 16) * 4 * 64;  // fragment-octet count
  prep_frags_kernel<<<(total + 255) / 256, 256, 0, stream>>>(embed, eh, el,
                                                             total);
  prep_e2_kernel<<<(K + 255) / 256, 256, 0, stream>>>(embed, e2d, K);
  vq_argmin_kernel<<<N / 64, 256, 0, stream>>>(x, embed, eh, el, e2d, out_q,
                                               out_i, K);
}

// Round 2
// 70.370 us; speedup vs baseline: 1.3815x; 1.3815x over previous
//
#include <hip/hip_runtime.h>

typedef _Float16 half8 __attribute__((ext_vector_type(8)));
typedef float f32x4 __attribute__((ext_vector_type(4)));

#define DD 128

// Workspace layout:
//   FRAG: nch records of 8192 B. Record c, octet idx=(s*2+hl) in 0..7 at
//         offset idx*1024 + lane*16: 8 f16 of code n=c*16+(lane&15),
//         k = s*32 + (lane>>4)*8 + 0..7.  hl=0 -> hi half, hl=1 -> lo half.
//   E2NEG (after FRAG): nch * 256 B. Record c, lane slot = float
//         -(||e_n||^2) for n = c*16 + (lane&15)  (replicated over lane>>4).

__global__ void prep_frags_kernel(const float* __restrict__ embed,
                                  char* __restrict__ frag, int total) {
  int t = blockIdx.x * blockDim.x + threadIdx.x;
  if (t >= total) return;
  int lane = t & 63;
  int idx = (t >> 6) & 7;
  int c = t >> 9;
  int s = idx >> 1;
  int hl = idx & 1;
  int n = c * 16 + (lane & 15);
  int kb = s * 32 + ((lane >> 4) << 3);
  const float* src = embed + (size_t)n * DD + kb;
  _Float16* dst = (_Float16*)(frag + (size_t)c * 8192 + idx * 1024 + lane * 16);
#pragma unroll
  for (int j = 0; j < 8; ++j) {
    float v = src[j];
    _Float16 hi = (_Float16)v;
    dst[j] = hl ? (_Float16)(v - (float)hi) : hi;
  }
}

__global__ void prep_e2_kernel(const float* __restrict__ embed,
                               float* __restrict__ e2neg, int total) {
  int t = blockIdx.x * blockDim.x + threadIdx.x;
  if (t >= total) return;
  int lane = t & 63;
  int c = t >> 6;
  int n = c * 16 + (lane & 15);
  const float* src = embed + (size_t)n * DD;
  double s = 0.0;
  for (int j = 0; j < DD; ++j) { double v = (double)src[j]; s += v * v; }
  e2neg[c * 64 + lane] = (float)(-s);
}

// ---------------------------------------------------------------------------
// Main: block = 256 thr (4 waves), wave owns 32 rows (2 row-tiles of 16).
// Per 16-code chunk: 24x mfma_f32_16x16x32_f16 (3-term f16 split x 2 tiles),
// fp32 score = fmaf(2, acc, -e2), running argmax. 2x unrolled ping-pong
// B prefetch (no register rotation). C/D: col=lane&15, row=(lane>>4)*4+reg.
// ---------------------------------------------------------------------------
__global__ __launch_bounds__(256) void vq_argmin_kernel(
    const float* __restrict__ x, const float* __restrict__ embed,
    const char* __restrict__ wsf, const float* __restrict__ wse,
    float* __restrict__ out_q, float* __restrict__ out_i, int nch) {
  const int lane = threadIdx.x & 63;
  const int w = threadIdx.x >> 6;
  const int m16 = lane & 15;
  const int g = lane >> 4;
  const int row0 = blockIdx.x * 128 + w * 32;

  // A fragments for 2 row-tiles, f16 hi/lo split
  half8 ah[2][4], al[2][4];
#pragma unroll
  for (int t = 0; t < 2; ++t) {
    const float* xrow = x + (size_t)(row0 + t * 16 + m16) * DD;
#pragma unroll
    for (int s = 0; s < 4; ++s) {
      const float* p = xrow + s * 32 + g * 8;
      f32x4 v0 = *(const f32x4*)(p);
      f32x4 v1 = *(const f32x4*)(p + 4);
#pragma unroll
      for (int j = 0; j < 4; ++j) {
        float v = v0[j];
        _Float16 hi = (_Float16)v;
        ah[t][s][j] = hi;
        al[t][s][j] = (_Float16)(v - (float)hi);
      }
#pragma unroll
      for (int j = 0; j < 4; ++j) {
        float v = v1[j];
        _Float16 hi = (_Float16)v;
        ah[t][s][4 + j] = hi;
        al[t][s][4 + j] = (_Float16)(v - (float)hi);
      }
    }
  }

  float bestv0[4], bestv1[4];
  int besti0[4], besti1[4];
#pragma unroll
  for (int r = 0; r < 4; ++r) {
    bestv0[r] = -__builtin_inff();
    bestv1[r] = -__builtin_inff();
    besti0[r] = 0;
    besti1[r] = 0;
  }

  half8 bhA[4], blA[4], bhB[4], blB[4];
  float neA, neB;

#define LOADB(BH, BL, NE, C)                                        \
  do {                                                              \
    const char* pf = wsf + (size_t)(C)*8192 + lane * 16;            \
    const char* pf1 = pf + 4096;                                    \
    BH[0] = *(const half8*)(pf);                                    \
    BL[0] = *(const half8*)(pf + 1024);                             \
    BH[1] = *(const half8*)(pf + 2048);                             \
    BL[1] = *(const half8*)(pf + 3072);                             \
    BH[2] = *(const half8*)(pf1);                                   \
    BL[2] = *(const half8*)(pf1 + 1024);                            \
    BH[3] = *(const half8*)(pf1 + 2048);                            \
    BL[3] = *(const half8*)(pf1 + 3072);                            \
    NE = wse[(size_t)(C)*64 + lane];                                \
  } while (0)

#define COMPUTE(BH, BL, NE, C)                                               \
  do {                                                                       \
    f32x4 acc0 = {0.f, 0.f, 0.f, 0.f};                                       \
    f32x4 acc1 = {0.f, 0.f, 0.f, 0.f};                                       \
    _Pragma("unroll") for (int s = 0; s < 4; ++s) {                          \
      acc0 = __builtin_amdgcn_mfma_f32_16x16x32_f16(ah[0][s], BH[s], acc0,   \
                                                    0, 0, 0);                \
      acc1 = __builtin_amdgcn_mfma_f32_16x16x32_f16(ah[1][s], BH[s], acc1,   \
                                                    0, 0, 0);                \
      acc0 = __builtin_amdgcn_mfma_f32_16x16x32_f16(al[0][s], BH[s], acc0,   \
                                                    0, 0, 0);                \
      acc1 = __builtin_amdgcn_mfma_f32_16x16x32_f16(al[1][s], BH[s], acc1,   \
                                                    0, 0, 0);                \
      acc0 = __builtin_amdgcn_mfma_f32_16x16x32_f16(ah[0][s], BL[s], acc0,   \
                                                    0, 0, 0);                \
      acc1 = __builtin_amdgcn_mfma_f32_16x16x32_f16(ah[1][s], BL[s], acc1,   \
                                                    0, 0, 0);                \
    }                                                                        \
    const int n_ = (C)*16 + m16;                                             \
    _Pragma("unroll") for (int r = 0; r < 4; ++r) {                          \
      float s0 = fmaf(2.f, acc0[r], NE);                                     \
      if (s0 > bestv0[r]) { bestv0[r] = s0; besti0[r] = n_; }                \
      float s1 = fmaf(2.f, acc1[r], NE);                                     \
      if (s1 > bestv1[r]) { bestv1[r] = s1; besti1[r] = n_; }                \
    }                                                                        \
  } while (0)

  LOADB(bhA, blA, neA, 0);
  for (int c = 0; c < nch; c += 2) {
    LOADB(bhB, blB, neB, c + 1);
    COMPUTE(bhA, blA, neA, c);
    if (c + 2 < nch) LOADB(bhA, blA, neA, c + 2);
    COMPUTE(bhB, blB, neB, c + 1);
  }
#undef LOADB
#undef COMPUTE

  // reduce across the 16 lanes sharing each C row; smaller index on tie
#pragma unroll
  for (int off = 1; off < 16; off <<= 1) {
#pragma unroll
    for (int r = 0; r < 4; ++r) {
      float ov0 = __shfl_xor(bestv0[r], off, 64);
      int oi0 = __shfl_xor(besti0[r], off, 64);
      if (ov0 > bestv0[r] || (ov0 == bestv0[r] && oi0 < besti0[r])) {
        bestv0[r] = ov0;
        besti0[r] = oi0;
      }
      float ov1 = __shfl_xor(bestv1[r], off, 64);
      int oi1 = __shfl_xor(besti1[r], off, 64);
      if (ov1 > bestv1[r] || (ov1 == bestv1[r] && oi1 < besti1[r])) {
        bestv1[r] = ov1;
        besti1[r] = oi1;
      }
    }
  }

  // outputs: index (as float) + gathered code row (16 lanes x 8 floats)
#pragma unroll
  for (int t = 0; t < 2; ++t) {
#pragma unroll
    for (int r = 0; r < 4; ++r) {
      const int row = row0 + t * 16 + g * 4 + r;
      const int idx = t ? besti1[r] : besti0[r];
      if (m16 == 0) out_i[row] = (float)idx;
      const f32x4* src = (const f32x4*)(embed + (size_t)idx * DD) + m16 * 2;
      f32x4* dst = (f32x4*)(out_q + (size_t)row * DD) + m16 * 2;
      dst[0] = src[0];
      dst[1] = src[1];
    }
  }
}

// ---------------------------------------------------------------------------
// Fallback: exact double-precision distance, thread per row.
// ---------------------------------------------------------------------------
__global__ void vq_fallback_kernel(const float* __restrict__ x,
                                   const float* __restrict__ embed,
                                   float* __restrict__ out_q,
                                   float* __restrict__ out_i, int N, int K) {
  int row = blockIdx.x * blockDim.x + threadIdx.x;
  if (row >= N) return;
  const float* xr = x + (size_t)row * DD;
  float xv[DD];
  for (int j = 0; j < DD; ++j) xv[j] = xr[j];
  double best = -1e300;
  int bi = 0;
  for (int k = 0; k < K; ++k) {
    const float* e = embed + (size_t)k * DD;
    double acc = 0.0;
    for (int j = 0; j < DD; ++j) {
      double d = (double)xv[j] - (double)e[j];
      acc += d * d;
    }
    double sc = -acc;
    if (sc > best) { best = sc; bi = k; }
  }
  out_i[row] = (float)bi;
  for (int j = 0; j < DD; ++j)
    out_q[(size_t)row * DD + j] = embed[(size_t)bi * DD + j];
}

extern "C" void kernel_launch(void* const* d_in, const int* in_sizes, int n_in,
                              void* d_out, int out_size, void* d_ws,
                              size_t ws_size, hipStream_t stream) {
  const float* x = (const float*)d_in[0];
  const float* embed = (const float*)d_in[1];
  const int N = in_sizes[0] / DD;  // 65536 rows
  const int K = in_sizes[1] / DD;  // 1024 codes
  float* out_q = (float*)d_out;
  float* out_i = out_q + (size_t)N * DD;

  const int nch = K / 16;
  const size_t frag_bytes = (size_t)nch * 8192;
  const size_t e2_bytes = (size_t)nch * 256;
  const size_t need = frag_bytes + e2_bytes;

  if (ws_size < need || (N % 128) != 0 || (K % 16) != 0) {
    vq_fallback_kernel<<<(N + 255) / 256, 256, 0, stream>>>(x, embed, out_q,
                                                            out_i, N, K);
    return;
  }

  char* wsf = (char*)d_ws;
  float* wse = (float*)(wsf + frag_bytes);

  const int total_f = nch * 8 * 64;
  prep_frags_kernel<<<(total_f + 255) / 256, 256, 0, stream>>>(embed, wsf,
                                                               total_f);
  const int total_e = nch * 64;
  prep_e2_kernel<<<(total_e + 255) / 256, 256, 0, stream>>>(embed, wse,
                                                            total_e);
  vq_argmin_kernel<<<N / 128, 256, 0, stream>>>(x, embed, wsf, wse, out_q,
                                                out_i, nch);
}